// Round 1
// baseline (310.525 us; speedup 1.0000x reference)
//
#include <hip/hip_runtime.h>
#include <cstdint>
#include <cstddef>

// Problem constants
#define NHEADS 16
#define HDIM   64
#define EMBED  1024
#define BATCH  2
#define SEQ    2048
#define BH     (BATCH*NHEADS)        // 32
#define MTOK   (BATCH*SEQ)           // 4096
#define NQKV   (3*NHEADS*HDIM)       // 3072

typedef _Float16 f16;
typedef __attribute__((ext_vector_type(4))) _Float16 f16x4;
typedef __attribute__((ext_vector_type(8))) _Float16 f16x8;
typedef __attribute__((ext_vector_type(4))) float f32x4;

// ---------------------------------------------------------------------------
// Transpose + fp32->f16 convert:  out[n][k] = (f16) in[k][n]
// in: [K][N] fp32 row-major, out: [N][K] f16 row-major
// ---------------------------------------------------------------------------
__global__ __launch_bounds__(256) void transpose_cvt_kernel(
    const float* __restrict__ in, f16* __restrict__ out, int K, int N)
{
    __shared__ float tile[32][33];
    const int n0 = blockIdx.x * 32;
    const int k0 = blockIdx.y * 32;
    const int tx = threadIdx.x & 31;
    const int ty = threadIdx.x >> 5;      // 0..7
#pragma unroll
    for (int j = 0; j < 4; ++j) {
        int k = ty + j * 8;
        tile[k][tx] = in[(size_t)(k0 + k) * N + n0 + tx];
    }
    __syncthreads();
#pragma unroll
    for (int j = 0; j < 4; ++j) {
        int n = ty + j * 8;
        out[(size_t)(n0 + n) * K + k0 + tx] = (f16)tile[tx][n];
    }
}

// ---------------------------------------------------------------------------
// GEMM1: QKV = X @ Wqkv + b  (M=4096, N=3072, K=1024)
// A = X fp32 (converted to f16 while staging), B = WqkvT f16 [N][K].
// Epilogue scatters to Q (scaled 1/8), K row-major [bh][s][d], V transposed
// [bh][d][s] so attention's PV B-operand reads contiguous keys.
// 128x128 tile, BK=32, 4 waves (2x2), each wave 64x64 via 4x4 MFMA 16x16x32.
// LDS rows are 64B; XOR-swizzle byte^=((row&3)<<4) => frag ds_read_b128 2-way.
// ---------------------------------------------------------------------------
__global__ __launch_bounds__(256, 2) void gemm_qkv_kernel(
    const float* __restrict__ X, const f16* __restrict__ WT,
    const float* __restrict__ bqkv,
    f16* __restrict__ Qb, f16* __restrict__ Kb, f16* __restrict__ Vt)
{
    __shared__ f16 As[128 * 32];
    __shared__ f16 Bs[128 * 32];
    const int tid = threadIdx.x;
    const int lane = tid & 63;
    const int wid = tid >> 6;
    const int wr = wid >> 1, wc = wid & 1;
    const int lhi = lane >> 4, llo = lane & 15;
    const int row0 = blockIdx.x * 128;
    const int col0 = blockIdx.y * 128;

    f32x4 acc[4][4] = {};

    for (int k0 = 0; k0 < EMBED; k0 += 32) {
        __syncthreads();
        // stage A: 128x32 fp32 -> f16 (thread: 4 x float4 -> f16x4)
#pragma unroll
        for (int i = 0; i < 4; ++i) {
            int li = i * 256 + tid;              // 0..1023 (4 elems each)
            int ar = li >> 3;                    // 0..127
            int ac = (li & 7) * 4;               // 0..28
            float4 v = *reinterpret_cast<const float4*>(
                &X[(size_t)(row0 + ar) * EMBED + k0 + ac]);
            int byte = (ac * 2) ^ ((ar & 3) << 4);
            f16x4 h;
            h[0] = (f16)v.x; h[1] = (f16)v.y; h[2] = (f16)v.z; h[3] = (f16)v.w;
            *reinterpret_cast<f16x4*>((char*)As + ar * 64 + byte) = h;
        }
        // stage B: 128x32 f16 (thread: 2 x 16B)
#pragma unroll
        for (int i = 0; i < 2; ++i) {
            int li = i * 256 + tid;              // 0..511 (8 elems each)
            int br = li >> 2;
            int bc = (li & 3) * 8;
            f16x8 v = *reinterpret_cast<const f16x8*>(
                &WT[(size_t)(col0 + br) * EMBED + k0 + bc]);
            int byte = (bc * 2) ^ ((br & 3) << 4);
            *reinterpret_cast<f16x8*>((char*)Bs + br * 64 + byte) = v;
        }
        __syncthreads();
        f16x8 af[4], bf[4];
#pragma unroll
        for (int m = 0; m < 4; ++m) {
            int ar = wr * 64 + m * 16 + llo;
            int byte = (lhi * 16) ^ ((ar & 3) << 4);
            af[m] = *reinterpret_cast<const f16x8*>((const char*)As + ar * 64 + byte);
        }
#pragma unroll
        for (int n = 0; n < 4; ++n) {
            int br = wc * 64 + n * 16 + llo;
            int byte = (lhi * 16) ^ ((br & 3) << 4);
            bf[n] = *reinterpret_cast<const f16x8*>((const char*)Bs + br * 64 + byte);
        }
#pragma unroll
        for (int m = 0; m < 4; ++m)
#pragma unroll
            for (int n = 0; n < 4; ++n)
                acc[m][n] = __builtin_amdgcn_mfma_f32_16x16x32_f16(
                    af[m], bf[n], acc[m][n], 0, 0, 0);
    }

    // epilogue: C layout col=lane&15, row=(lane>>4)*4+reg  [verified, guide §3]
#pragma unroll
    for (int m = 0; m < 4; ++m) {
#pragma unroll
        for (int n = 0; n < 4; ++n) {
#pragma unroll
            for (int r = 0; r < 4; ++r) {
                int mg = row0 + wr * 64 + m * 16 + lhi * 4 + r;
                int ng = col0 + wc * 64 + n * 16 + llo;
                float v = acc[m][n][r] + bqkv[ng];
                int t = ng >> 10;
                int h = (ng >> 6) & 15;
                int d = ng & 63;
                int b = mg >> 11;
                int s = mg & (SEQ - 1);
                int bh = b * NHEADS + h;
                if (t == 0)
                    Qb[((size_t)bh * SEQ + s) * HDIM + d] = (f16)(v * 0.125f);
                else if (t == 1)
                    Kb[((size_t)bh * SEQ + s) * HDIM + d] = (f16)v;
                else
                    Vt[((size_t)bh * HDIM + d) * SEQ + s] = (f16)v;
            }
        }
    }
}

// ---------------------------------------------------------------------------
// Flash attention: grid (S/64, BH); 4 waves/block, each wave owns 16 Q rows.
// Q pre-scaled by 1/sqrt(64). Per 32-key step: 4 QK MFMAs -> online softmax
// (16-lane shfl_xor reduce) -> P f16 via per-wave swizzled LDS transpose ->
// 4 PV MFMAs into f32 acc.  K/V stream from global (L2-resident, 512KB/head).
// ---------------------------------------------------------------------------
__global__ __launch_bounds__(256, 2) void attn_kernel(
    const f16* __restrict__ Qb, const f16* __restrict__ Kb,
    const f16* __restrict__ Vt, f16* __restrict__ ctx)
{
    __shared__ f16 Pl[4][16 * 32];   // 1KB per wave
    const int tid = threadIdx.x;
    const int lane = tid & 63;
    const int wid = tid >> 6;
    const int lhi = lane >> 4, llo = lane & 15;
    const int bh = blockIdx.y;
    const int q0 = blockIdx.x * 64 + wid * 16;
    const f16* Qp = Qb + (size_t)bh * SEQ * HDIM;
    const f16* Kp = Kb + (size_t)bh * SEQ * HDIM;
    const f16* Vp = Vt + (size_t)bh * HDIM * SEQ;
    char* plbase = (char*)&Pl[wid][0];

    f16x8 qf[2];
#pragma unroll
    for (int h = 0; h < 2; ++h)
        qf[h] = *reinterpret_cast<const f16x8*>(
            &Qp[(size_t)(q0 + llo) * HDIM + h * 32 + lhi * 8]);

    f32x4 o[4] = {};
    float mrow[4], lrow[4];
#pragma unroll
    for (int r = 0; r < 4; ++r) { mrow[r] = -1e30f; lrow[r] = 0.f; }

    for (int kb = 0; kb < SEQ; kb += 32) {
        f32x4 s[2];
#pragma unroll
        for (int j = 0; j < 2; ++j) {
            f16x8 kf0 = *reinterpret_cast<const f16x8*>(
                &Kp[(size_t)(kb + j * 16 + llo) * HDIM + lhi * 8]);
            f16x8 kf1 = *reinterpret_cast<const f16x8*>(
                &Kp[(size_t)(kb + j * 16 + llo) * HDIM + 32 + lhi * 8]);
            f32x4 z = {0.f, 0.f, 0.f, 0.f};
            f32x4 t = __builtin_amdgcn_mfma_f32_16x16x32_f16(qf[0], kf0, z, 0, 0, 0);
            s[j] = __builtin_amdgcn_mfma_f32_16x16x32_f16(qf[1], kf1, t, 0, 0, 0);
        }
        // row max across 16 cols (lanes within group of 16)
        float pm[4];
#pragma unroll
        for (int r = 0; r < 4; ++r) pm[r] = fmaxf(s[0][r], s[1][r]);
#pragma unroll
        for (int msk = 1; msk < 16; msk <<= 1)
#pragma unroll
            for (int r = 0; r < 4; ++r)
                pm[r] = fmaxf(pm[r], __shfl_xor(pm[r], msk, 64));

        float ssum[4];
#pragma unroll
        for (int r = 0; r < 4; ++r) {
            float nm = fmaxf(mrow[r], pm[r]);
            float sc = __expf(mrow[r] - nm);
            mrow[r] = nm;
            float p0 = __expf(s[0][r] - nm);
            float p1 = __expf(s[1][r] - nm);
            s[0][r] = p0; s[1][r] = p1;
            ssum[r] = p0 + p1;
            lrow[r] *= sc;
#pragma unroll
            for (int n = 0; n < 4; ++n) o[n][r] *= sc;
        }
#pragma unroll
        for (int msk = 1; msk < 16; msk <<= 1)
#pragma unroll
            for (int r = 0; r < 4; ++r)
                ssum[r] += __shfl_xor(ssum[r], msk, 64);
#pragma unroll
        for (int r = 0; r < 4; ++r) lrow[r] += ssum[r];

        // P -> LDS (swizzled), then read back as MFMA A-frag (16B/lane)
#pragma unroll
        for (int j = 0; j < 2; ++j)
#pragma unroll
            for (int r = 0; r < 4; ++r) {
                int prow = lhi * 4 + r;
                int pcol = j * 16 + llo;
                int byte = (pcol * 2) ^ ((prow & 3) << 4);
                *reinterpret_cast<f16*>(plbase + prow * 64 + byte) = (f16)s[j][r];
            }
        {
            int byte = (lhi * 16) ^ ((llo & 3) << 4);
            f16x8 pa = *reinterpret_cast<const f16x8*>(plbase + llo * 64 + byte);
#pragma unroll
            for (int n = 0; n < 4; ++n) {
                f16x8 vf = *reinterpret_cast<const f16x8*>(
                    &Vp[(size_t)(n * 16 + llo) * SEQ + kb + lhi * 8]);
                o[n] = __builtin_amdgcn_mfma_f32_16x16x32_f16(pa, vf, o[n], 0, 0, 0);
            }
        }
    }

    const int b = bh >> 4;
    const int h = bh & 15;
#pragma unroll
    for (int n = 0; n < 4; ++n)
#pragma unroll
        for (int r = 0; r < 4; ++r) {
            int q = q0 + lhi * 4 + r;
            int d = n * 16 + llo;
            float v = o[n][r] / lrow[r];
            ctx[((size_t)(b * SEQ + q)) * EMBED + h * HDIM + d] = (f16)v;
        }
}

// ---------------------------------------------------------------------------
// GEMM2: out = ctx @ Wo + bo  (M=4096, N=1024, K=1024), fp32 output.
// ---------------------------------------------------------------------------
__global__ __launch_bounds__(256, 2) void gemm_out_kernel(
    const f16* __restrict__ A, const f16* __restrict__ WT,
    const float* __restrict__ bo, float* __restrict__ out)
{
    __shared__ f16 As[128 * 32];
    __shared__ f16 Bs[128 * 32];
    const int tid = threadIdx.x;
    const int lane = tid & 63;
    const int wid = tid >> 6;
    const int wr = wid >> 1, wc = wid & 1;
    const int lhi = lane >> 4, llo = lane & 15;
    const int row0 = blockIdx.x * 128;
    const int col0 = blockIdx.y * 128;

    f32x4 acc[4][4] = {};

    for (int k0 = 0; k0 < EMBED; k0 += 32) {
        __syncthreads();
#pragma unroll
        for (int i = 0; i < 2; ++i) {
            int li = i * 256 + tid;
            int ar = li >> 2;
            int ac = (li & 3) * 8;
            f16x8 v = *reinterpret_cast<const f16x8*>(
                &A[(size_t)(row0 + ar) * EMBED + k0 + ac]);
            int byte = (ac * 2) ^ ((ar & 3) << 4);
            *reinterpret_cast<f16x8*>((char*)As + ar * 64 + byte) = v;
        }
#pragma unroll
        for (int i = 0; i < 2; ++i) {
            int li = i * 256 + tid;
            int br = li >> 2;
            int bc = (li & 3) * 8;
            f16x8 v = *reinterpret_cast<const f16x8*>(
                &WT[(size_t)(col0 + br) * EMBED + k0 + bc]);
            int byte = (bc * 2) ^ ((br & 3) << 4);
            *reinterpret_cast<f16x8*>((char*)Bs + br * 64 + byte) = v;
        }
        __syncthreads();
        f16x8 af[4], bf[4];
#pragma unroll
        for (int m = 0; m < 4; ++m) {
            int ar = wr * 64 + m * 16 + llo;
            int byte = (lhi * 16) ^ ((ar & 3) << 4);
            af[m] = *reinterpret_cast<const f16x8*>((const char*)As + ar * 64 + byte);
        }
#pragma unroll
        for (int n = 0; n < 4; ++n) {
            int br = wc * 64 + n * 16 + llo;
            int byte = (lhi * 16) ^ ((br & 3) << 4);
            bf[n] = *reinterpret_cast<const f16x8*>((const char*)Bs + br * 64 + byte);
        }
#pragma unroll
        for (int m = 0; m < 4; ++m)
#pragma unroll
            for (int n = 0; n < 4; ++n)
                acc[m][n] = __builtin_amdgcn_mfma_f32_16x16x32_f16(
                    af[m], bf[n], acc[m][n], 0, 0, 0);
    }

#pragma unroll
    for (int m = 0; m < 4; ++m)
#pragma unroll
        for (int n = 0; n < 4; ++n)
#pragma unroll
            for (int r = 0; r < 4; ++r) {
                int mg = row0 + wr * 64 + m * 16 + lhi * 4 + r;
                int ng = col0 + wc * 64 + n * 16 + llo;
                out[(size_t)mg * EMBED + ng] = acc[m][n][r] + bo[ng];
            }
}

// ---------------------------------------------------------------------------
extern "C" void kernel_launch(void* const* d_in, const int* in_sizes, int n_in,
                              void* d_out, int out_size, void* d_ws, size_t ws_size,
                              hipStream_t stream)
{
    const float* x     = (const float*)d_in[0];
    const float* w_qkv = (const float*)d_in[1];
    const float* b_qkv = (const float*)d_in[2];
    const float* w_o   = (const float*)d_in[3];
    const float* b_o   = (const float*)d_in[4];
    float* out = (float*)d_out;

    char* ws = (char*)d_ws;
    f16* wqkvT = (f16*)ws; ws += (size_t)NQKV * EMBED * 2;       // 6 MB
    f16* woT   = (f16*)ws; ws += (size_t)EMBED * EMBED * 2;      // 2 MB
    f16* Qb    = (f16*)ws; ws += (size_t)BH * SEQ * HDIM * 2;    // 8 MB
    f16* Kb    = (f16*)ws; ws += (size_t)BH * SEQ * HDIM * 2;    // 8 MB
    f16* Vt    = (f16*)ws; ws += (size_t)BH * SEQ * HDIM * 2;    // 8 MB
    f16* ctx   = (f16*)ws; ws += (size_t)MTOK * EMBED * 2;       // 8 MB  (40 MB total)

    hipLaunchKernelGGL(transpose_cvt_kernel, dim3(NQKV / 32, EMBED / 32), dim3(256),
                       0, stream, w_qkv, wqkvT, EMBED, NQKV);
    hipLaunchKernelGGL(transpose_cvt_kernel, dim3(EMBED / 32, EMBED / 32), dim3(256),
                       0, stream, w_o, woT, EMBED, EMBED);
    hipLaunchKernelGGL(gemm_qkv_kernel, dim3(MTOK / 128, NQKV / 128), dim3(256),
                       0, stream, x, wqkvT, b_qkv, Qb, Kb, Vt);
    hipLaunchKernelGGL(attn_kernel, dim3(SEQ / 64, BH), dim3(256),
                       0, stream, Qb, Kb, Vt, ctx);
    hipLaunchKernelGGL(gemm_out_kernel, dim3(MTOK / 128, EMBED / 128), dim3(256),
                       0, stream, ctx, woT, b_o, out);
}

// Round 2
// 198.710 us; speedup vs baseline: 1.5627x; 1.5627x over previous
//
#include <hip/hip_runtime.h>
#include <cstdint>
#include <cstddef>

// Problem constants
#define NHEADS 16
#define HDIM   64
#define EMBED  1024
#define BATCH  2
#define SEQ    2048
#define BH     (BATCH*NHEADS)        // 32
#define MTOK   (BATCH*SEQ)           // 4096
#define NQKV   (3*NHEADS*HDIM)       // 3072

typedef _Float16 f16;
typedef __attribute__((ext_vector_type(4))) _Float16 f16x4;
typedef __attribute__((ext_vector_type(8))) _Float16 f16x8;
typedef __attribute__((ext_vector_type(4))) float f32x4;
typedef __attribute__((ext_vector_type(16))) float f32x16;

// pack two f32 -> one u32 of 2 f16 (RTZ)
__device__ __forceinline__ unsigned pkf16(float a, float b) {
    return __builtin_bit_cast(unsigned, __builtin_amdgcn_cvt_pkrtz(a, b));
}

// ---------------------------------------------------------------------------
// Transpose + fp32->f16 convert:  out[n][k] = (f16) in[k][n]
// ---------------------------------------------------------------------------
__global__ __launch_bounds__(256) void transpose_cvt_kernel(
    const float* __restrict__ in, f16* __restrict__ out, int K, int N)
{
    __shared__ float tile[32][33];
    const int n0 = blockIdx.x * 32;
    const int k0 = blockIdx.y * 32;
    const int tx = threadIdx.x & 31;
    const int ty = threadIdx.x >> 5;
#pragma unroll
    for (int j = 0; j < 4; ++j) {
        int k = ty + j * 8;
        tile[k][tx] = in[(size_t)(k0 + k) * N + n0 + tx];
    }
    __syncthreads();
#pragma unroll
    for (int j = 0; j < 4; ++j) {
        int n = ty + j * 8;
        out[(size_t)(n0 + n) * K + k0 + tx] = (f16)tile[tx][n];
    }
}

// ---------------------------------------------------------------------------
// GEMM1: QKV = X @ Wqkv + b  (M=4096, N=3072, K=1024)
// Epilogue scatters Q (scaled 0.125*log2e for base-2 softmax), K row-major,
// V transposed [bh][d][s].
// ---------------------------------------------------------------------------
__global__ __launch_bounds__(256, 2) void gemm_qkv_kernel(
    const float* __restrict__ X, const f16* __restrict__ WT,
    const float* __restrict__ bqkv,
    f16* __restrict__ Qb, f16* __restrict__ Kb, f16* __restrict__ Vt)
{
    __shared__ f16 As[128 * 32];
    __shared__ f16 Bs[128 * 32];
    const int tid = threadIdx.x;
    const int lane = tid & 63;
    const int wid = tid >> 6;
    const int wr = wid >> 1, wc = wid & 1;
    const int lhi = lane >> 4, llo = lane & 15;
    const int row0 = blockIdx.x * 128;
    const int col0 = blockIdx.y * 128;

    f32x4 acc[4][4] = {};

    for (int k0 = 0; k0 < EMBED; k0 += 32) {
        __syncthreads();
#pragma unroll
        for (int i = 0; i < 4; ++i) {
            int li = i * 256 + tid;
            int ar = li >> 3;
            int ac = (li & 7) * 4;
            float4 v = *reinterpret_cast<const float4*>(
                &X[(size_t)(row0 + ar) * EMBED + k0 + ac]);
            int byte = (ac * 2) ^ ((ar & 3) << 4);
            f16x4 h;
            h[0] = (f16)v.x; h[1] = (f16)v.y; h[2] = (f16)v.z; h[3] = (f16)v.w;
            *reinterpret_cast<f16x4*>((char*)As + ar * 64 + byte) = h;
        }
#pragma unroll
        for (int i = 0; i < 2; ++i) {
            int li = i * 256 + tid;
            int br = li >> 2;
            int bc = (li & 3) * 8;
            f16x8 v = *reinterpret_cast<const f16x8*>(
                &WT[(size_t)(col0 + br) * EMBED + k0 + bc]);
            int byte = (bc * 2) ^ ((br & 3) << 4);
            *reinterpret_cast<f16x8*>((char*)Bs + br * 64 + byte) = v;
        }
        __syncthreads();
        f16x8 af[4], bf[4];
#pragma unroll
        for (int m = 0; m < 4; ++m) {
            int ar = wr * 64 + m * 16 + llo;
            int byte = (lhi * 16) ^ ((ar & 3) << 4);
            af[m] = *reinterpret_cast<const f16x8*>((const char*)As + ar * 64 + byte);
        }
#pragma unroll
        for (int n = 0; n < 4; ++n) {
            int br = wc * 64 + n * 16 + llo;
            int byte = (lhi * 16) ^ ((br & 3) << 4);
            bf[n] = *reinterpret_cast<const f16x8*>((const char*)Bs + br * 64 + byte);
        }
#pragma unroll
        for (int m = 0; m < 4; ++m)
#pragma unroll
            for (int n = 0; n < 4; ++n)
                acc[m][n] = __builtin_amdgcn_mfma_f32_16x16x32_f16(
                    af[m], bf[n], acc[m][n], 0, 0, 0);
    }

#pragma unroll
    for (int m = 0; m < 4; ++m) {
#pragma unroll
        for (int n = 0; n < 4; ++n) {
#pragma unroll
            for (int r = 0; r < 4; ++r) {
                int mg = row0 + wr * 64 + m * 16 + lhi * 4 + r;
                int ng = col0 + wc * 64 + n * 16 + llo;
                float v = acc[m][n][r] + bqkv[ng];
                int t = ng >> 10;
                int h = (ng >> 6) & 15;
                int d = ng & 63;
                int b = mg >> 11;
                int s = mg & (SEQ - 1);
                int bh = b * NHEADS + h;
                if (t == 0)
                    Qb[((size_t)bh * SEQ + s) * HDIM + d] = (f16)(v * 0.18033688011f);
                else if (t == 1)
                    Kb[((size_t)bh * SEQ + s) * HDIM + d] = (f16)v;
                else
                    Vt[((size_t)bh * HDIM + d) * SEQ + s] = (f16)v;
            }
        }
    }
}

// ---------------------------------------------------------------------------
// Flash attention, swapped-operand in-register softmax (guide §B m214 style).
// Grid (BH, SEQ/128); 4 waves/block, each wave owns 32 q rows, KVBLK=64.
// S^T = mfma(K, Q): lane q=lane&31, k=crow(r,hi)=(r&3)+8*(r>>2)+4*(lane>>5).
// O^T = mfma(V^T, P^T): same lane->q mapping as softmax state (rescale is
// per-lane). P packed f32->f16 via cvt_pkrtz + v_permlane32_swap_b32 (T12).
// Base-2 softmax (Q pre-scaled by 0.125*log2e); defer-max THR=8 (T13).
// K/V direct from global: per head 512KB, L2-resident; grid x=head pins a
// head to one XCD (16x L2 reuse across q-tiles).
// ---------------------------------------------------------------------------
__global__ __launch_bounds__(256) void attn_kernel(
    const f16* __restrict__ Qb, const f16* __restrict__ Kb,
    const f16* __restrict__ Vt, f16* __restrict__ ctx)
{
    __shared__ f16 Ol[4][32 * 64];   // 16KB: per-warp output transpose patch
    const int tid = threadIdx.x;
    const int lane = tid & 63;
    const int wid = tid >> 6;
    const int q = lane & 31;
    const int hi = lane >> 5;
    const int bh = blockIdx.x;
    const int q0 = blockIdx.y * 128 + wid * 32;
    const f16* Qp = Qb + (size_t)bh * SEQ * HDIM;
    const f16* Kp = Kb + (size_t)bh * SEQ * HDIM;
    const f16* Vp = Vt + (size_t)bh * HDIM * SEQ;

    // Q-frags (B-operand of QK^T): lane needs Q[q0+q][ds*16 + 8*hi + j]
    f16x8 qf[4];
#pragma unroll
    for (int ds = 0; ds < 4; ++ds)
        qf[ds] = *reinterpret_cast<const f16x8*>(
            Qp + (size_t)(q0 + q) * HDIM + ds * 16 + hi * 8);

    f32x16 o[2] = {};
    float m = -1e30f, l = 0.f;

    for (int kb = 0; kb < SEQ; kb += 64) {
        // ---- QK^T (swapped): st[kt] covers k = kb + kt*32 + crow(r,hi)
        f32x16 st[2] = {};
        const f16* kbase = Kp + (size_t)kb * HDIM;
#pragma unroll
        for (int ds = 0; ds < 4; ++ds) {
            f16x8 kf0 = *reinterpret_cast<const f16x8*>(
                kbase + (size_t)q * HDIM + ds * 16 + hi * 8);
            f16x8 kf1 = *reinterpret_cast<const f16x8*>(
                kbase + (size_t)(32 + q) * HDIM + ds * 16 + hi * 8);
            st[0] = __builtin_amdgcn_mfma_f32_32x32x16_f16(kf0, qf[ds], st[0], 0, 0, 0);
            st[1] = __builtin_amdgcn_mfma_f32_32x32x16_f16(kf1, qf[ds], st[1], 0, 0, 0);
        }

        // ---- online softmax, in-register (base-2 domain)
        float pm = -1e30f;
#pragma unroll
        for (int t = 0; t < 2; ++t)
#pragma unroll
            for (int r = 0; r < 16; ++r) pm = fmaxf(pm, st[t][r]);
        pm = fmaxf(pm, __shfl_xor(pm, 32, 64));

        if (!__all(pm - m <= 8.0f)) {           // defer-max (T13)
            float mn = fmaxf(m, pm);
            float sc = __builtin_amdgcn_exp2f(m - mn);
            m = mn;
            l *= sc;
#pragma unroll
            for (int t = 0; t < 2; ++t)
#pragma unroll
                for (int r = 0; r < 16; ++r) o[t][r] *= sc;
        }

        float p[2][16];
        float ps = 0.f;
#pragma unroll
        for (int t = 0; t < 2; ++t)
#pragma unroll
            for (int r = 0; r < 16; ++r) {
                p[t][r] = __builtin_amdgcn_exp2f(st[t][r] - m);
                ps += p[t][r];
            }
        l += ps;

        // ---- pack P into B-frags (P^T): 16 cvt_pk + 8 permlane32_swap
        f16x8 pf[4];
#pragma unroll
        for (int t = 0; t < 2; ++t) {
            unsigned a0 = pkf16(p[t][0], p[t][1]);
            unsigned a1 = pkf16(p[t][2], p[t][3]);
            unsigned b0 = pkf16(p[t][4], p[t][5]);
            unsigned b1 = pkf16(p[t][6], p[t][7]);
            unsigned c0 = pkf16(p[t][8], p[t][9]);
            unsigned c1 = pkf16(p[t][10], p[t][11]);
            unsigned d0 = pkf16(p[t][12], p[t][13]);
            unsigned d1 = pkf16(p[t][14], p[t][15]);
            asm("v_permlane32_swap_b32 %0, %1" : "+v"(a0), "+v"(b0));
            asm("v_permlane32_swap_b32 %0, %1" : "+v"(a1), "+v"(b1));
            asm("v_permlane32_swap_b32 %0, %1" : "+v"(c0), "+v"(d0));
            asm("v_permlane32_swap_b32 %0, %1" : "+v"(c1), "+v"(d1));
            uint4 w0; w0.x = a0; w0.y = a1; w0.z = b0; w0.w = b1;
            uint4 w1; w1.x = c0; w1.y = c1; w1.z = d0; w1.w = d1;
            pf[t * 2 + 0] = __builtin_bit_cast(f16x8, w0);
            pf[t * 2 + 1] = __builtin_bit_cast(f16x8, w1);
        }

        // ---- PV (swapped): O^T[d][q] += V^T-frag x P^T-frag
        const f16* vbase = Vp + kb;
#pragma unroll
        for (int dt = 0; dt < 2; ++dt)
#pragma unroll
            for (int f = 0; f < 4; ++f) {
                f16x8 vf = *reinterpret_cast<const f16x8*>(
                    vbase + (size_t)(dt * 32 + q) * SEQ + f * 16 + hi * 8);
                o[dt] = __builtin_amdgcn_mfma_f32_32x32x16_f16(vf, pf[f], o[dt], 0, 0, 0);
            }
    }

    // ---- epilogue: normalize, transpose via swizzled LDS, coalesced store
    float lt = l + __shfl_xor(l, 32, 64);
    float inv = __builtin_amdgcn_rcpf(lt);
    char* base = (char*)&Ol[wid][0];
#pragma unroll
    for (int dt = 0; dt < 2; ++dt)
#pragma unroll
        for (int rp = 0; rp < 8; ++rp) {
            int r = rp * 2;
            int d = dt * 32 + (r & 3) + 8 * (r >> 2) + 4 * hi;
            unsigned w = pkf16(o[dt][r] * inv, o[dt][r + 1] * inv);
            int byte = (q * 128 + d * 2) ^ ((q & 7) << 4);
            *reinterpret_cast<unsigned*>(base + byte) = w;
        }
    __syncthreads();
    {
        int row = lane >> 1, half = lane & 1;
        const char* rb = base + row * 128;
        int b = bh >> 4, h = bh & 15;
        f16* orow = ctx + (size_t)(b * SEQ + q0 + row) * EMBED + h * HDIM;
#pragma unroll
        for (int i = 0; i < 4; ++i) {
            int c = half * 64 + i * 16;
            int4 v = *reinterpret_cast<const int4*>(rb + (c ^ ((row & 7) << 4)));
            *reinterpret_cast<int4*>((char*)orow + c) = v;
        }
    }
}

// ---------------------------------------------------------------------------
// GEMM2: out = ctx @ Wo + bo  (M=4096, N=1024, K=1024), fp32 output.
// ---------------------------------------------------------------------------
__global__ __launch_bounds__(256, 2) void gemm_out_kernel(
    const f16* __restrict__ A, const f16* __restrict__ WT,
    const float* __restrict__ bo, float* __restrict__ out)
{
    __shared__ f16 As[128 * 32];
    __shared__ f16 Bs[128 * 32];
    const int tid = threadIdx.x;
    const int lane = tid & 63;
    const int wid = tid >> 6;
    const int wr = wid >> 1, wc = wid & 1;
    const int lhi = lane >> 4, llo = lane & 15;
    const int row0 = blockIdx.x * 128;
    const int col0 = blockIdx.y * 128;

    f32x4 acc[4][4] = {};

    for (int k0 = 0; k0 < EMBED; k0 += 32) {
        __syncthreads();
#pragma unroll
        for (int i = 0; i < 2; ++i) {
            int li = i * 256 + tid;
            int ar = li >> 2;
            int ac = (li & 3) * 8;
            f16x8 v = *reinterpret_cast<const f16x8*>(
                &A[(size_t)(row0 + ar) * EMBED + k0 + ac]);
            int byte = (ac * 2) ^ ((ar & 3) << 4);
            *reinterpret_cast<f16x8*>((char*)As + ar * 64 + byte) = v;
        }
#pragma unroll
        for (int i = 0; i < 2; ++i) {
            int li = i * 256 + tid;
            int br = li >> 2;
            int bc = (li & 3) * 8;
            f16x8 v = *reinterpret_cast<const f16x8*>(
                &WT[(size_t)(col0 + br) * EMBED + k0 + bc]);
            int byte = (bc * 2) ^ ((br & 3) << 4);
            *reinterpret_cast<f16x8*>((char*)Bs + br * 64 + byte) = v;
        }
        __syncthreads();
        f16x8 af[4], bf[4];
#pragma unroll
        for (int m = 0; m < 4; ++m) {
            int ar = wr * 64 + m * 16 + llo;
            int byte = (lhi * 16) ^ ((ar & 3) << 4);
            af[m] = *reinterpret_cast<const f16x8*>((const char*)As + ar * 64 + byte);
        }
#pragma unroll
        for (int n = 0; n < 4; ++n) {
            int br = wc * 64 + n * 16 + llo;
            int byte = (lhi * 16) ^ ((br & 3) << 4);
            bf[n] = *reinterpret_cast<const f16x8*>((const char*)Bs + br * 64 + byte);
        }
#pragma unroll
        for (int m = 0; m < 4; ++m)
#pragma unroll
            for (int n = 0; n < 4; ++n)
                acc[m][n] = __builtin_amdgcn_mfma_f32_16x16x32_f16(
                    af[m], bf[n], acc[m][n], 0, 0, 0);
    }

#pragma unroll
    for (int m = 0; m < 4; ++m)
#pragma unroll
        for (int n = 0; n < 4; ++n)
#pragma unroll
            for (int r = 0; r < 4; ++r) {
                int mg = row0 + wr * 64 + m * 16 + lhi * 4 + r;
                int ng = col0 + wc * 64 + n * 16 + llo;
                out[(size_t)mg * EMBED + ng] = acc[m][n][r] + bo[ng];
            }
}

// ---------------------------------------------------------------------------
extern "C" void kernel_launch(void* const* d_in, const int* in_sizes, int n_in,
                              void* d_out, int out_size, void* d_ws, size_t ws_size,
                              hipStream_t stream)
{
    const float* x     = (const float*)d_in[0];
    const float* w_qkv = (const float*)d_in[1];
    const float* b_qkv = (const float*)d_in[2];
    const float* w_o   = (const float*)d_in[3];
    const float* b_o   = (const float*)d_in[4];
    float* out = (float*)d_out;

    char* ws = (char*)d_ws;
    f16* wqkvT = (f16*)ws; ws += (size_t)NQKV * EMBED * 2;
    f16* woT   = (f16*)ws; ws += (size_t)EMBED * EMBED * 2;
    f16* Qb    = (f16*)ws; ws += (size_t)BH * SEQ * HDIM * 2;
    f16* Kb    = (f16*)ws; ws += (size_t)BH * SEQ * HDIM * 2;
    f16* Vt    = (f16*)ws; ws += (size_t)BH * SEQ * HDIM * 2;
    f16* ctx   = (f16*)ws; ws += (size_t)MTOK * EMBED * 2;

    hipLaunchKernelGGL(transpose_cvt_kernel, dim3(NQKV / 32, EMBED / 32), dim3(256),
                       0, stream, w_qkv, wqkvT, EMBED, NQKV);
    hipLaunchKernelGGL(transpose_cvt_kernel, dim3(EMBED / 32, EMBED / 32), dim3(256),
                       0, stream, w_o, woT, EMBED, EMBED);
    hipLaunchKernelGGL(gemm_qkv_kernel, dim3(MTOK / 128, NQKV / 128), dim3(256),
                       0, stream, x, wqkvT, b_qkv, Qb, Kb, Vt);
    hipLaunchKernelGGL(attn_kernel, dim3(BH, SEQ / 128), dim3(256),
                       0, stream, Qb, Kb, Vt, ctx);
    hipLaunchKernelGGL(gemm_out_kernel, dim3(MTOK / 128, EMBED / 128), dim3(256),
                       0, stream, ctx, woT, b_o, out);
}